// Round 1
// baseline (1006.036 us; speedup 1.0000x reference)
//
#include <hip/hip_runtime.h>

// SoftDTW forward, B=64, T=1024, D=8, gamma=1.0, out = mean over batch of R[T,T].
//
// Design:
//  - one block per batch element (64 blocks, 512 threads = 8 waves)
//  - thread t owns rows [2t, 2t+2); each step processes a 2x4 tile of cells
//  - anti-diagonal wavefront over steps s: thread t active for q = s-t in [0,256)
//  - target staged in LDS as 128B q-blocks (4 rows x 8 dims), 16B chunks
//    XOR-swizzled by (q&7) so ds_read_b128 at 128B lane stride doesn't all
//    land in bank 0
//  - frontier row "hrow" (R[bottom-of-processed][j]) in LDS with staggered
//    index e(h)=h+(h>>3) to break the 4-element lane stride
//  - diagonal corner carried in a register (previous step's top-right read,
//    saved BEFORE overwrite) -- the LDS slot gets clobbered by our own
//    bottom-row write, so it must not be re-read
//  - dist via norms: d = |p|^2 + |t|^2 - 2 p.t  (pred rows + norms in regs)
//  - softmin = m - ln2*log2(sum exp2((m-x)*log2e)), m = min3  (exp(0)=1 safe)

static constexpr int T     = 1024;
static constexpr int Dd    = 8;
static constexpr int NB    = 64;
static constexpr int NTH   = 512;          // threads per block
static constexpr int CT    = 4;            // cols per step-tile
static constexpr int NQ    = T / CT;       // 256 col-tiles per row band
static constexpr int NSTEP = NTH + NQ - 1; // 767 wavefront steps

#define BIGF 1e10f
#define L2EF 1.4426950408889634f
#define LN2F 0.6931471805599453f

__device__ __forceinline__ int eh(int h) { return h + (h >> 3); }

__device__ __forceinline__ float softmin3(float a, float b, float c) {
  float m = fminf(fminf(a, b), c);
  float s = exp2f((m - a) * L2EF) + exp2f((m - b) * L2EF) + exp2f((m - c) * L2EF);
  return m - LN2F * log2f(s);
}

#define DOT8(pa, pb, ta, tb)                                            \
  (((pa.x * ta.x + pa.y * ta.y) + (pa.z * ta.z + pa.w * ta.w)) +        \
   ((pb.x * tb.x + pb.y * tb.y) + (pb.z * tb.z + pb.w * tb.w)))

__device__ __forceinline__ float cellv(float pnn, float tnn, float dot,
                                       float dl, float ac, float lf) {
  float d = fmaf(dot, -2.0f, pnn + tnn);
  return d + softmin3(dl, ac, lf);
}

__global__ __launch_bounds__(NTH) void sdtw_kernel(const float* __restrict__ pred,
                                                   const float* __restrict__ target,
                                                   float* __restrict__ ws) {
  __shared__ float4 tgt_s[T * Dd / 4]; // 2048 float4 = 32 KiB, swizzled chunks
  __shared__ float hrow_s[1153];       // e(1024)=1152
  __shared__ float tn_s[1151];         // e(1023)=1150

  const int t = threadIdx.x;
  const int b = blockIdx.x;
  const float* pr = pred + (size_t)b * T * Dd;
  const float* tg = target + (size_t)b * T * Dd;

  // ---- stage target into LDS (swizzled) + compute target norms -------------
  {
    const float4* tg4 = reinterpret_cast<const float4*>(tg);
    float4 v0 = tg4[t * 4 + 0];
    float4 v1 = tg4[t * 4 + 1];
    float4 v2 = tg4[t * 4 + 2];
    float4 v3 = tg4[t * 4 + 3];
    // thread t's 16 floats are exactly rows 2t and 2t+1
    float tn0 = (v0.x * v0.x + v0.y * v0.y) + (v0.z * v0.z + v0.w * v0.w) +
                (v1.x * v1.x + v1.y * v1.y) + (v1.z * v1.z + v1.w * v1.w);
    float tn1 = (v2.x * v2.x + v2.y * v2.y) + (v2.z * v2.z + v2.w * v2.w) +
                (v3.x * v3.x + v3.y * v3.y) + (v3.z * v3.z + v3.w * v3.w);
    float4 vv[4] = {v0, v1, v2, v3};
#pragma unroll
    for (int k = 0; k < 4; ++k) {
      int g = 4 * t + k;      // global 16B chunk id
      int q = g >> 3;         // q-block (4 target rows)
      int ch = g & 7;         // logical chunk within block
      tgt_s[q * 8 + (ch ^ (q & 7))] = vv[k];
    }
    tn_s[eh(2 * t + 0)] = tn0;
    tn_s[eh(2 * t + 1)] = tn1;
  }

  // ---- init frontier: hrow[h] over h=0..1024; h=0 is R[-1][-1]=0 -----------
  for (int h = t; h <= T; h += NTH) hrow_s[eh(h)] = (h == 0) ? 0.0f : BIGF;

  // ---- pred rows (2 per thread) + norms into registers ---------------------
  const float4* pr4 = reinterpret_cast<const float4*>(pr);
  float4 pA0 = pr4[t * 4 + 0];
  float4 pA1 = pr4[t * 4 + 1];
  float4 pB0 = pr4[t * 4 + 2];
  float4 pB1 = pr4[t * 4 + 3];
  float pn0 = (pA0.x * pA0.x + pA0.y * pA0.y) + (pA0.z * pA0.z + pA0.w * pA0.w) +
              (pA1.x * pA1.x + pA1.y * pA1.y) + (pA1.z * pA1.z + pA1.w * pA1.w);
  float pn1 = (pB0.x * pB0.x + pB0.y * pB0.y) + (pB0.z * pB0.z + pB0.w * pB0.w) +
              (pB1.x * pB1.x + pB1.y * pB1.y) + (pB1.z * pB1.z + pB1.w * pB1.w);

  __syncthreads();

  // ---- wavefront sweep -----------------------------------------------------
  float l0 = BIGF, l1 = BIGF; // left boundary R[2t][j0-1], R[2t+1][j0-1]
  float carry = BIGF;         // R[2t-1][j0-1] for next step (pre-overwrite a3)

  for (int s = 0; s < NSTEP; ++s) {
    const int q = s - t;
    if (q >= 0 && q < NQ) {
      const int j0 = q * CT;

      // top boundary (row 2t-1) at cols j0..j0+3, written by thread t-1 last step
      float a0 = hrow_s[eh(j0 + 1)];
      float a1 = hrow_s[eh(j0 + 2)];
      float a2 = hrow_s[eh(j0 + 3)];
      float a3 = hrow_s[eh(j0 + 4)];
      float c0 = (q == 0) ? hrow_s[eh(0)] : carry; // corner R[2t-1][j0-1]
      float a3o = a3;                              // save: next step's corner
      if (q == 0 && t == 0) hrow_s[eh(0)] = BIGF;  // after our read of R[-1][-1]=0

      // target q-block (4 rows x 8 dims), unswizzle chunks
      const int qb = q * 8, x = q & 7;
      float4 t0a = tgt_s[qb + (0 ^ x)];
      float4 t0b = tgt_s[qb + (1 ^ x)];
      float4 t1a = tgt_s[qb + (2 ^ x)];
      float4 t1b = tgt_s[qb + (3 ^ x)];
      float4 t2a = tgt_s[qb + (4 ^ x)];
      float4 t2b = tgt_s[qb + (5 ^ x)];
      float4 t3a = tgt_s[qb + (6 ^ x)];
      float4 t3b = tgt_s[qb + (7 ^ x)];
      float tn0 = tn_s[eh(j0 + 0)];
      float tn1 = tn_s[eh(j0 + 1)];
      float tn2 = tn_s[eh(j0 + 2)];
      float tn3 = tn_s[eh(j0 + 3)];

      const float l0in = l0;

      // row 0 (global row 2t)
      float dl = c0, lf = l0, v;
      v = cellv(pn0, tn0, DOT8(pA0, pA1, t0a, t0b), dl, a0, lf); dl = a0; a0 = v; lf = v;
      v = cellv(pn0, tn1, DOT8(pA0, pA1, t1a, t1b), dl, a1, lf); dl = a1; a1 = v; lf = v;
      v = cellv(pn0, tn2, DOT8(pA0, pA1, t2a, t2b), dl, a2, lf); dl = a2; a2 = v; lf = v;
      v = cellv(pn0, tn3, DOT8(pA0, pA1, t3a, t3b), dl, a3, lf); dl = a3; a3 = v; lf = v;
      l0 = lf;

      // row 1 (global row 2t+1); diag starts at old left of row 0
      dl = l0in; lf = l1;
      v = cellv(pn1, tn0, DOT8(pB0, pB1, t0a, t0b), dl, a0, lf); dl = a0; a0 = v; lf = v;
      v = cellv(pn1, tn1, DOT8(pB0, pB1, t1a, t1b), dl, a1, lf); dl = a1; a1 = v; lf = v;
      v = cellv(pn1, tn2, DOT8(pB0, pB1, t2a, t2b), dl, a2, lf); dl = a2; a2 = v; lf = v;
      v = cellv(pn1, tn3, DOT8(pB0, pB1, t3a, t3b), dl, a3, lf); dl = a3; a3 = v; lf = v;
      l1 = lf;

      // publish bottom row (2t+1) at cols j0..j0+3
      hrow_s[eh(j0 + 1)] = a0;
      hrow_s[eh(j0 + 2)] = a1;
      hrow_s[eh(j0 + 3)] = a2;
      hrow_s[eh(j0 + 4)] = a3;

      carry = a3o;

      if (t == NTH - 1 && q == NQ - 1) ws[b] = a3; // R[1023][1023]
    }
    __syncthreads();
  }
}

__global__ void sdtw_reduce(const float* __restrict__ ws, float* __restrict__ out) {
  int l = threadIdx.x; // 64 threads = one wave
  float v = ws[l];
#pragma unroll
  for (int k = 32; k >= 1; k >>= 1) v += __shfl_down(v, k, 64);
  if (l == 0) out[0] = v * (1.0f / (float)NB);
}

extern "C" void kernel_launch(void* const* d_in, const int* in_sizes, int n_in,
                              void* d_out, int out_size, void* d_ws, size_t ws_size,
                              hipStream_t stream) {
  const float* pred   = (const float*)d_in[0];
  const float* target = (const float*)d_in[1];
  float* out = (float*)d_out;
  float* ws  = (float*)d_ws;

  sdtw_kernel<<<NB, NTH, 0, stream>>>(pred, target, ws);
  sdtw_reduce<<<1, 64, 0, stream>>>(ws, out);
}

// Round 3
// 554.137 us; speedup vs baseline: 1.8155x; 1.8155x over previous
//
#include <hip/hip_runtime.h>

// SoftDTW forward, B=64, T=1024, D=8, gamma=1.0, out = mean over batch of R[T,T].
//
// R3 = R2 design (barrier-free wave staircase) with HIP-correct fast-math
// intrinsics: __builtin_amdgcn_exp2f / __builtin_amdgcn_logf (v_exp_f32 /
// v_log_f32 directly; __exp2f/__log2f are CUDA-only and broke the build).
//
//  - one block per batch (64 blocks x 512 threads = 8 waves)
//  - thread t owns rows [2t, 2t+2); per step a 2x4 tile of cells
//  - WITHIN a wave, the 64 lanes form the anti-diagonal staircase in lockstep:
//    lane l processes col-tile q = sw - l. Lane l's hrow LDS write at step sw
//    is ordered before lane l+1's read at step sw+1 by in-order DS issue ->
//    no barrier needed intra-wave.
//  - ONLY lane 0 of wave w depends on wave w-1 (lane 63's bottom row).
//    Cross-wave sync: per-wave progress counter in LDS, release-store by
//    producer each step, acquire-load spin by consumer (rare after fill).
//  - NO __syncthreads in the main loop (one at start after staging).
//  - math kept in base-2 log2e units: target staged as -2*log2e*t, norms
//    pre-scaled, dist = seed + 8 FMA; softmin = min3 + 3 exp2 + log2.
//    Final result scaled by ln2 once.

static constexpr int T      = 1024;
static constexpr int Dd     = 8;
static constexpr int NB     = 64;
static constexpr int NTH    = 512;          // 8 waves
static constexpr int NW     = NTH / 64;     // 8
static constexpr int CT     = 4;            // cols per tile
static constexpr int NQ     = T / CT;       // 256 col-tiles
static constexpr int WSTEPS = NQ + 63;      // 319 per-wave staircase steps

#define BIGF 1e10f
#define L2EF 1.4426950408889634f
#define LN2F 0.6931471805599453f

__device__ __forceinline__ int eh(int h) { return h + (h >> 3); }

__device__ __forceinline__ float fexp2(float x) { return __builtin_amdgcn_exp2f(x); }
__device__ __forceinline__ float flog2(float x) { return __builtin_amdgcn_logf(x); }

// softmin in base-2 domain: returns m - log2(sum 2^(m-x))
__device__ __forceinline__ float softmin2(float a, float b, float c) {
  float m = fminf(fminf(a, b), c);
  float s = fexp2(m - a) + fexp2(m - b) + fexp2(m - c);
  return m - flog2(s);
}

// d2 = pn2 + tn2 - 2*log2e*(p.t), with target pre-scaled by -2*log2e
__device__ __forceinline__ float dot8s(float seed, const float4& pa, const float4& pb,
                                       const float4& ta, const float4& tb) {
  float acc = seed;
  acc = fmaf(pa.x, ta.x, acc); acc = fmaf(pa.y, ta.y, acc);
  acc = fmaf(pa.z, ta.z, acc); acc = fmaf(pa.w, ta.w, acc);
  acc = fmaf(pb.x, tb.x, acc); acc = fmaf(pb.y, tb.y, acc);
  acc = fmaf(pb.z, tb.z, acc); acc = fmaf(pb.w, tb.w, acc);
  return acc;
}

__global__ __launch_bounds__(NTH) void sdtw_kernel(const float* __restrict__ pred,
                                                   const float* __restrict__ target,
                                                   float* __restrict__ ws) {
  __shared__ float4 tgt_s[T * Dd / 4]; // 2048 float4 = 32 KiB, swizzled chunks
  __shared__ float hrow_s[1153];       // e(1024)=1152, staggered
  __shared__ float tn_s[1151];         // staggered
  __shared__ int prog_s[NW];

  const int t    = threadIdx.x;
  const int w    = t >> 6;
  const int lane = t & 63;
  const int b    = blockIdx.x;
  const float* pr = pred + (size_t)b * T * Dd;
  const float* tg = target + (size_t)b * T * Dd;

  // ---- stage target into LDS (swizzled, scaled by -2*log2e) + norms -------
  {
    const float4* tg4 = reinterpret_cast<const float4*>(tg);
    float4 v0 = tg4[t * 4 + 0];
    float4 v1 = tg4[t * 4 + 1];
    float4 v2 = tg4[t * 4 + 2];
    float4 v3 = tg4[t * 4 + 3];
    float tn0 = (v0.x * v0.x + v0.y * v0.y) + (v0.z * v0.z + v0.w * v0.w) +
                (v1.x * v1.x + v1.y * v1.y) + (v1.z * v1.z + v1.w * v1.w);
    float tn1 = (v2.x * v2.x + v2.y * v2.y) + (v2.z * v2.z + v2.w * v2.w) +
                (v3.x * v3.x + v3.y * v3.y) + (v3.z * v3.z + v3.w * v3.w);
    const float s = -2.0f * L2EF;
    float4 vv[4];
    float4 vs;
    vs.x = v0.x * s; vs.y = v0.y * s; vs.z = v0.z * s; vs.w = v0.w * s; vv[0] = vs;
    vs.x = v1.x * s; vs.y = v1.y * s; vs.z = v1.z * s; vs.w = v1.w * s; vv[1] = vs;
    vs.x = v2.x * s; vs.y = v2.y * s; vs.z = v2.z * s; vs.w = v2.w * s; vv[2] = vs;
    vs.x = v3.x * s; vs.y = v3.y * s; vs.z = v3.z * s; vs.w = v3.w * s; vv[3] = vs;
#pragma unroll
    for (int k = 0; k < 4; ++k) {
      int g = 4 * t + k;
      int q = g >> 3;
      int ch = g & 7;
      tgt_s[q * 8 + (ch ^ (q & 7))] = vv[k];
    }
    tn_s[eh(2 * t + 0)] = tn0 * L2EF;
    tn_s[eh(2 * t + 1)] = tn1 * L2EF;
  }

  // ---- init: wave 0 owns the whole hrow init (only its lane 0 reads it) ---
  if (w == 0)
    for (int h = lane; h <= T; h += 64) hrow_s[eh(h)] = BIGF;
  if (lane == 0) prog_s[w] = -1;

  // ---- pred rows (2 per thread) + scaled norms into registers -------------
  const float4* pr4 = reinterpret_cast<const float4*>(pr);
  float4 pA0 = pr4[t * 4 + 0];
  float4 pA1 = pr4[t * 4 + 1];
  float4 pB0 = pr4[t * 4 + 2];
  float4 pB1 = pr4[t * 4 + 3];
  float pn0 = ((pA0.x * pA0.x + pA0.y * pA0.y) + (pA0.z * pA0.z + pA0.w * pA0.w) +
               (pA1.x * pA1.x + pA1.y * pA1.y) + (pA1.z * pA1.z + pA1.w * pA1.w)) * L2EF;
  float pn1 = ((pB0.x * pB0.x + pB0.y * pB0.y) + (pB0.z * pB0.z + pB0.w * pB0.w) +
               (pB1.x * pB1.x + pB1.y * pB1.y) + (pB1.z * pB1.z + pB1.w * pB1.w)) * L2EF;

  __syncthreads(); // only barrier: staging + init complete

  // ---- barrier-free wavefront ---------------------------------------------
  float l0 = BIGF, l1 = BIGF;
  float carry = (t == 0) ? 0.0f : BIGF; // R[2t-1][-1]; R[-1][-1]=0 for t==0

  for (int sw = 0; sw < WSTEPS; ++sw) {
    // cross-wave guard: lane 0 of wave w needs wave w-1's lane 63 at step 63+sw
    if (w > 0 && sw < NQ) {
      const int need = 63 + sw;
      while (__hip_atomic_load(&prog_s[w - 1], __ATOMIC_ACQUIRE,
                               __HIP_MEMORY_SCOPE_WORKGROUP) < need)
        __builtin_amdgcn_s_sleep(1);
    }

    const int q = sw - lane;
    if (q >= 0 && q < NQ) {
      const int j0 = q * CT;

      float a0 = hrow_s[eh(j0 + 1)];
      float a1 = hrow_s[eh(j0 + 2)];
      float a2 = hrow_s[eh(j0 + 3)];
      float a3 = hrow_s[eh(j0 + 4)];
      const float c0  = carry;
      const float a3o = a3;

      const int qb = q * 8, x = q & 7;
      float4 t0a = tgt_s[qb + (0 ^ x)];
      float4 t0b = tgt_s[qb + (1 ^ x)];
      float4 t1a = tgt_s[qb + (2 ^ x)];
      float4 t1b = tgt_s[qb + (3 ^ x)];
      float4 t2a = tgt_s[qb + (4 ^ x)];
      float4 t2b = tgt_s[qb + (5 ^ x)];
      float4 t3a = tgt_s[qb + (6 ^ x)];
      float4 t3b = tgt_s[qb + (7 ^ x)];
      float tn0 = tn_s[eh(j0 + 0)];
      float tn1 = tn_s[eh(j0 + 1)];
      float tn2 = tn_s[eh(j0 + 2)];
      float tn3 = tn_s[eh(j0 + 3)];

      // dist terms (independent FMA chains, off critical path)
      float d00 = dot8s(pn0 + tn0, pA0, pA1, t0a, t0b);
      float d01 = dot8s(pn0 + tn1, pA0, pA1, t1a, t1b);
      float d02 = dot8s(pn0 + tn2, pA0, pA1, t2a, t2b);
      float d03 = dot8s(pn0 + tn3, pA0, pA1, t3a, t3b);
      float d10 = dot8s(pn1 + tn0, pB0, pB1, t0a, t0b);
      float d11 = dot8s(pn1 + tn1, pB0, pB1, t1a, t1b);
      float d12 = dot8s(pn1 + tn2, pB0, pB1, t2a, t2b);
      float d13 = dot8s(pn1 + tn3, pB0, pB1, t3a, t3b);

      const float l0in = l0;
      float dl, lf, v;

      // row 0 (global row 2t)
      dl = c0; lf = l0;
      v = d00 + softmin2(dl, a0, lf); dl = a0; a0 = v; lf = v;
      v = d01 + softmin2(dl, a1, lf); dl = a1; a1 = v; lf = v;
      v = d02 + softmin2(dl, a2, lf); dl = a2; a2 = v; lf = v;
      v = d03 + softmin2(dl, a3, lf); dl = a3; a3 = v; lf = v;
      l0 = lf;

      // row 1 (global row 2t+1)
      dl = l0in; lf = l1;
      v = d10 + softmin2(dl, a0, lf); dl = a0; a0 = v; lf = v;
      v = d11 + softmin2(dl, a1, lf); dl = a1; a1 = v; lf = v;
      v = d12 + softmin2(dl, a2, lf); dl = a2; a2 = v; lf = v;
      v = d13 + softmin2(dl, a3, lf); dl = a3; a3 = v; lf = v;
      l1 = lf;

      hrow_s[eh(j0 + 1)] = a0;
      hrow_s[eh(j0 + 2)] = a1;
      hrow_s[eh(j0 + 3)] = a2;
      hrow_s[eh(j0 + 4)] = a3;

      carry = a3o;

      if (t == NTH - 1 && q == NQ - 1) ws[b] = a3 * LN2F; // R[1023][1023]
    }

    // publish progress (release orders the hrow writes above)
    if (lane == 63)
      __hip_atomic_store(&prog_s[w], sw, __ATOMIC_RELEASE,
                         __HIP_MEMORY_SCOPE_WORKGROUP);
  }
}

__global__ void sdtw_reduce(const float* __restrict__ ws, float* __restrict__ out) {
  int l = threadIdx.x; // 64 threads = one wave
  float v = ws[l];
#pragma unroll
  for (int k = 32; k >= 1; k >>= 1) v += __shfl_down(v, k, 64);
  if (l == 0) out[0] = v * (1.0f / (float)NB);
}

extern "C" void kernel_launch(void* const* d_in, const int* in_sizes, int n_in,
                              void* d_out, int out_size, void* d_ws, size_t ws_size,
                              hipStream_t stream) {
  const float* pred   = (const float*)d_in[0];
  const float* target = (const float*)d_in[1];
  float* out = (float*)d_out;
  float* ws  = (float*)d_ws;

  sdtw_kernel<<<NB, NTH, 0, stream>>>(pred, target, ws);
  sdtw_reduce<<<1, 64, 0, stream>>>(ws, out);
}

// Round 4
// 485.520 us; speedup vs baseline: 2.0721x; 1.1413x over previous
//
#include <hip/hip_runtime.h>

// SoftDTW forward, B=64, T=1024, D=8, gamma=1.0, out = mean over batch of R[T,T].
//
// R4: register-staircase with shuffle handoff.
//  - one block per batch (64 blocks x 512 threads = 8 waves)
//  - thread t owns rows [2t, 2t+2); per step a 2x2 tile (CT=2), NQ=512 tiles
//  - top boundary comes from lane-1 via __shfl_up (2 values) -- no LDS
//    write/read round-trip on the critical chain. Diagonal corner = own
//    register (previous received a1). Left edge = own registers l0/l1.
//  - lane 0 reads the previous wave's lane-63 outputs from a full-size LDS
//    buffer (512 float2 per wave boundary, no ring overwrite hazard),
//    wave-uniform broadcast read.
//  - cross-wave sync amortized: producer lane 63 release-publishes prog
//    every 4 steps; consumer caches `seen` and re-checks every 4 steps.
//  - target staged as 5 x float4 per 2-col tile (4 data chunks + norms in
//    the pad slot): 80B stride = 8 distinct bank starts (b128 floor),
//    double-buffered prefetch in named registers (macro, rule #20 safe).
//  - math in base-2 units: d*log2e = seed + 8 FMA (target pre-scaled by
//    -2*log2e); softmin = min3 + 3 exp2 + log2; one *ln2 at the end.

static constexpr int T      = 1024;
static constexpr int NB     = 64;
static constexpr int NTH    = 512;       // 8 waves
static constexpr int NW     = 8;
static constexpr int CT     = 2;
static constexpr int NQ     = T / CT;    // 512 col-tiles
static constexpr int WSTEPS = NQ + 63;   // 575 per-wave staircase steps

#define BIGF 1e10f
#define L2EF 1.4426950408889634f
#define LN2F 0.6931471805599453f

__device__ __forceinline__ float fexp2(float x) { return __builtin_amdgcn_exp2f(x); }
__device__ __forceinline__ float flog2(float x) { return __builtin_amdgcn_logf(x); }

// softmin in base-2 domain: m - log2(2^(m-a) + 2^(m-b) + 2^(m-c)); m-x <= 0
// so exp2 never overflows; BIG inputs give exp2(-1e10)=0 (grad-safe analog).
__device__ __forceinline__ float softmin2(float a, float b, float c) {
  float m = fminf(fminf(a, b), c);
  float s = fexp2(m - a) + fexp2(m - b) + fexp2(m - c);
  return m - flog2(s);
}

// seed + p.t(scaled): d*log2e with seed = (|p|^2+|t|^2)*log2e, t pre-scaled by -2*log2e
__device__ __forceinline__ float dot8s(float seed, const float4& pa, const float4& pb,
                                       const float4& ta, const float4& tb) {
  float acc = seed;
  acc = fmaf(pa.x, ta.x, acc); acc = fmaf(pa.y, ta.y, acc);
  acc = fmaf(pa.z, ta.z, acc); acc = fmaf(pa.w, ta.w, acc);
  acc = fmaf(pb.x, tb.x, acc); acc = fmaf(pb.y, tb.y, acc);
  acc = fmaf(pb.z, tb.z, acc); acc = fmaf(pb.w, tb.w, acc);
  return acc;
}

// One staircase step. CUR/NXT are named float4[5] register arrays (constant
// indices only -> stay in VGPRs). Shuffles execute for ALL lanes (no
// divergence); state updates (l0,l1,carry,v10,v11) commit only when active.
#define STEP(SW, CUR, NXT)                                                   \
  {                                                                          \
    const int sw_ = (SW);                                                    \
    float2 cb = make_float2(BIGF, BIGF);                                     \
    if (w > 0 && sw_ < NQ) {                                                 \
      if ((sw_ & 3) == 0) {                                                  \
        const int need = ((sw_ + 3 < NQ) ? sw_ + 3 : NQ - 1) + 63;           \
        while (seen < need) {                                                 \
          seen = __hip_atomic_load(&prog_s[w - 1], __ATOMIC_ACQUIRE,         \
                                   __HIP_MEMORY_SCOPE_WORKGROUP);            \
          if (seen < need) __builtin_amdgcn_s_sleep(1);                      \
        }                                                                    \
      }                                                                      \
      cb = buf_s[(w - 1) * NQ + sw_]; /* wave-uniform broadcast read */      \
    }                                                                        \
    float na0 = __shfl_up(v10, 1, 64);                                       \
    float na1 = __shfl_up(v11, 1, 64);                                       \
    float a0 = (lane == 0) ? cb.x : na0;                                     \
    float a1 = (lane == 0) ? cb.y : na1;                                     \
    const int q = sw_ - lane;                                                \
    { /* prefetch next tile into NXT (clamped; junk-safe for idle lanes) */  \
      int qn = sw_ + 1 - lane;                                               \
      qn = qn < 0 ? 0 : (qn > NQ - 1 ? NQ - 1 : qn);                         \
      const float4* bp = &tgt4_s[qn * 5];                                    \
      NXT[0] = bp[0]; NXT[1] = bp[1]; NXT[2] = bp[2]; NXT[3] = bp[3];        \
      NXT[4] = bp[4];                                                        \
    }                                                                        \
    if (q >= 0 && q < NQ) {                                                  \
      const float tn0 = CUR[4].x, tn1 = CUR[4].y;                            \
      float d00 = dot8s(pn0 + tn0, pA0, pA1, CUR[0], CUR[1]);                \
      float d01 = dot8s(pn0 + tn1, pA0, pA1, CUR[2], CUR[3]);                \
      float d10 = dot8s(pn1 + tn0, pB0, pB1, CUR[0], CUR[1]);                \
      float d11 = dot8s(pn1 + tn1, pB0, pB1, CUR[2], CUR[3]);                \
      float v00 = d00 + softmin2(carry, a0, l0);                             \
      float v01 = d01 + softmin2(a0, a1, v00);                               \
      v10 = d10 + softmin2(l0, v00, l1);                                     \
      v11 = d11 + softmin2(v00, v01, v10);                                   \
      l0 = v01; l1 = v11; carry = a1;                                        \
      if (lane == 63 && w < NW - 1)                                          \
        buf_s[w * NQ + q] = make_float2(v10, v11);                           \
      if (t == NTH - 1 && q == NQ - 1) ws[b] = v11 * LN2F;                   \
    }                                                                        \
    if (lane == 63 && w < NW - 1 && ((sw_ & 3) == 3 || sw_ == WSTEPS - 1))   \
      __hip_atomic_store(&prog_s[w], sw_, __ATOMIC_RELEASE,                  \
                         __HIP_MEMORY_SCOPE_WORKGROUP);                      \
  }

__global__ __launch_bounds__(NTH) void sdtw_kernel(const float* __restrict__ pred,
                                                   const float* __restrict__ target,
                                                   float* __restrict__ ws) {
  __shared__ float4 tgt4_s[NQ * 5];       // 2560 float4 = 40 KiB
  __shared__ float2 buf_s[(NW - 1) * NQ]; // 7*512*8B = 28 KiB handoff
  __shared__ int prog_s[NW];

  const int t    = threadIdx.x;
  const int w    = t >> 6;
  const int lane = t & 63;
  const int b    = blockIdx.x;
  const float* pr = pred + (size_t)b * T * 8;
  const float* tg = target + (size_t)b * T * 8;

  // ---- stage target: thread t owns tile t (target rows 2t, 2t+1) ---------
  {
    const float4* tg4 = reinterpret_cast<const float4*>(tg);
    float4 v0 = tg4[t * 4 + 0];
    float4 v1 = tg4[t * 4 + 1];
    float4 v2 = tg4[t * 4 + 2];
    float4 v3 = tg4[t * 4 + 3];
    float tn0 = (v0.x * v0.x + v0.y * v0.y) + (v0.z * v0.z + v0.w * v0.w) +
                (v1.x * v1.x + v1.y * v1.y) + (v1.z * v1.z + v1.w * v1.w);
    float tn1 = (v2.x * v2.x + v2.y * v2.y) + (v2.z * v2.z + v2.w * v2.w) +
                (v3.x * v3.x + v3.y * v3.y) + (v3.z * v3.z + v3.w * v3.w);
    const float s = -2.0f * L2EF;
    float4 w0 = make_float4(v0.x * s, v0.y * s, v0.z * s, v0.w * s);
    float4 w1 = make_float4(v1.x * s, v1.y * s, v1.z * s, v1.w * s);
    float4 w2 = make_float4(v2.x * s, v2.y * s, v2.z * s, v2.w * s);
    float4 w3 = make_float4(v3.x * s, v3.y * s, v3.z * s, v3.w * s);
    tgt4_s[t * 5 + 0] = w0;
    tgt4_s[t * 5 + 1] = w1;
    tgt4_s[t * 5 + 2] = w2;
    tgt4_s[t * 5 + 3] = w3;
    tgt4_s[t * 5 + 4] = make_float4(tn0 * L2EF, tn1 * L2EF, 0.0f, 0.0f);
  }
  if (t < NW) prog_s[t] = -1;

  // ---- pred rows (2 per thread) + scaled norms in registers ---------------
  const float4* pr4 = reinterpret_cast<const float4*>(pr);
  float4 pA0 = pr4[t * 4 + 0];
  float4 pA1 = pr4[t * 4 + 1];
  float4 pB0 = pr4[t * 4 + 2];
  float4 pB1 = pr4[t * 4 + 3];
  float pn0 = ((pA0.x * pA0.x + pA0.y * pA0.y) + (pA0.z * pA0.z + pA0.w * pA0.w) +
               (pA1.x * pA1.x + pA1.y * pA1.y) + (pA1.z * pA1.z + pA1.w * pA1.w)) * L2EF;
  float pn1 = ((pB0.x * pB0.x + pB0.y * pB0.y) + (pB0.z * pB0.z + pB0.w * pB0.w) +
               (pB1.x * pB1.x + pB1.y * pB1.y) + (pB1.z * pB1.z + pB1.w * pB1.w)) * L2EF;

  __syncthreads(); // staging complete (only block-wide barrier)

  // ---- DP state ------------------------------------------------------------
  float l0 = BIGF, l1 = BIGF;                 // left edge R[2t][j-1], R[2t+1][j-1]
  float carry = (t == 0) ? 0.0f : BIGF;       // diag R[2t-1][j-1]; R[-1][-1]=0
  float v10 = BIGF, v11 = BIGF;               // bottom-row outputs (shuffled down)
  int seen = -1;

  float4 tgA[5], tgB[5];
  { // preload for sw=0: q = max(0-lane,0) = 0 for all lanes
    const float4* bp = &tgt4_s[0];
    tgA[0] = bp[0]; tgA[1] = bp[1]; tgA[2] = bp[2]; tgA[3] = bp[3]; tgA[4] = bp[4];
  }

  for (int sw = 0; sw < 576; sw += 2) { // 576 >= WSTEPS; extra step is inert
    STEP(sw, tgA, tgB)
    STEP(sw + 1, tgB, tgA)
  }
}

__global__ void sdtw_reduce(const float* __restrict__ ws, float* __restrict__ out) {
  int l = threadIdx.x; // 64 threads = one wave
  float v = ws[l];
#pragma unroll
  for (int k = 32; k >= 1; k >>= 1) v += __shfl_down(v, k, 64);
  if (l == 0) out[0] = v * (1.0f / (float)NB);
}

extern "C" void kernel_launch(void* const* d_in, const int* in_sizes, int n_in,
                              void* d_out, int out_size, void* d_ws, size_t ws_size,
                              hipStream_t stream) {
  const float* pred   = (const float*)d_in[0];
  const float* target = (const float*)d_in[1];
  float* out = (float*)d_out;
  float* ws  = (float*)d_ws;

  sdtw_kernel<<<NB, NTH, 0, stream>>>(pred, target, ws);
  sdtw_reduce<<<1, 64, 0, stream>>>(ws, out);
}

// Round 5
// 448.780 us; speedup vs baseline: 2.2417x; 1.0819x over previous
//
#include <hip/hip_runtime.h>

// SoftDTW forward, B=64, T=1024, D=8, gamma=1.0, out = mean over batch of R[T,T].
//
// R5 = R4 skeleton (register staircase, shuffle handoff, amortized cross-wave
// sync -- all unchanged) with the VALU diet:
//  - softmin via min3/med3/max3: 3 transcendentals per cell (was 4). Trans are
//    quarter-rate (~16cyc/wave64, fitted from R4's VALUBusy) -> biggest lever.
//  - dots via v_pk_fma_f32 (packed f32, inline asm on VGPR pairs): 16 pk_fma
//    per 2x2 tile instead of 32 scalar FMA. Pred rows pre-duplicated into
//    pair registers (loop-invariant); target tile staged dim-interleaved so
//    each float4 chunk = two pk operands for (col0,col1).
//  - tile = 4 x float4 (64B stride, 2-way bank alias = free) + separate
//    float2 norms array (1 ds_read_b64/step).
//  - prefetch issued AFTER shuffles: shuffle consumption waits lgkmcnt(5),
//    prefetch latency hides under compute.

typedef float v2f __attribute__((ext_vector_type(2)));

static constexpr int T      = 1024;
static constexpr int NB     = 64;
static constexpr int NTH    = 512;       // 8 waves
static constexpr int NW     = 8;
static constexpr int CT     = 2;
static constexpr int NQ     = T / CT;    // 512 col-tiles
static constexpr int WSTEPS = NQ + 63;   // 575 per-wave staircase steps

#define BIGF 1e10f
#define L2EF 1.4426950408889634f
#define LN2F 0.6931471805599453f

__device__ __forceinline__ float fexp2(float x) { return __builtin_amdgcn_exp2f(x); }
__device__ __forceinline__ float flog2(float x) { return __builtin_amdgcn_logf(x); }

// softmin in base-2 domain, 3 trans: m - log2(1 + 2^(m-med) + 2^(m-max)).
// min3/max3 fold to v_min3_f32/v_max3_f32; med3 is a builtin. m-x <= 0 so
// exp2 never overflows; BIG gaps underflow to 0 (grad-safe analog).
__device__ __forceinline__ float softmin2(float a, float b, float c) {
  float m = fminf(fminf(a, b), c);
  float M = fmaxf(fmaxf(a, b), c);
  float e = __builtin_amdgcn_fmed3f(a, b, c);
  float s = fexp2(m - e) + fexp2(m - M);
  return m - flog2(1.0f + s);
}

__device__ __forceinline__ v2f pkfma(v2f a, v2f b, v2f c) {
  v2f d;
  asm("v_pk_fma_f32 %0, %1, %2, %3" : "=v"(d) : "v"(a), "v"(b), "v"(c));
  return d;
}

__device__ __forceinline__ v2f lo2(const float4& c) { v2f r; r.x = c.x; r.y = c.y; return r; }
__device__ __forceinline__ v2f hi2(const float4& c) { v2f r; r.x = c.z; r.y = c.w; return r; }

// (dot_col0, dot_col1) for one pred row (duplicated pairs pp[0..7]) against
// the dim-interleaved tile chunks C[0..3]; seed = (pn+tn0, pn+tn1) scaled.
__device__ __forceinline__ v2f dotpk(v2f seed, const v2f* pp, const float4* C) {
  v2f a = seed;
  a = pkfma(pp[0], lo2(C[0]), a);
  a = pkfma(pp[1], hi2(C[0]), a);
  a = pkfma(pp[2], lo2(C[1]), a);
  a = pkfma(pp[3], hi2(C[1]), a);
  a = pkfma(pp[4], lo2(C[2]), a);
  a = pkfma(pp[5], hi2(C[2]), a);
  a = pkfma(pp[6], lo2(C[3]), a);
  a = pkfma(pp[7], hi2(C[3]), a);
  return a;
}

// One staircase step. CUR/NXT: named float4[4] reg tiles; CN/NN: float2 norms.
#define STEP(SW, CUR, CN, NXT, NN)                                           \
  {                                                                          \
    const int sw_ = (SW);                                                    \
    float2 cb = make_float2(BIGF, BIGF);                                     \
    if (w > 0 && sw_ < NQ) {                                                 \
      if ((sw_ & 3) == 0) {                                                  \
        const int need = ((sw_ + 3 < NQ) ? sw_ + 3 : NQ - 1) + 63;           \
        while (seen < need) {                                                 \
          seen = __hip_atomic_load(&prog_s[w - 1], __ATOMIC_ACQUIRE,         \
                                   __HIP_MEMORY_SCOPE_WORKGROUP);            \
          if (seen < need) __builtin_amdgcn_s_sleep(1);                      \
        }                                                                    \
      }                                                                      \
      cb = buf_s[(w - 1) * NQ + sw_]; /* wave-uniform broadcast read */      \
    }                                                                        \
    float na0 = __shfl_up(v10, 1, 64);                                       \
    float na1 = __shfl_up(v11, 1, 64);                                       \
    float a0 = (lane == 0) ? cb.x : na0;                                     \
    float a1 = (lane == 0) ? cb.y : na1;                                     \
    const int q = sw_ - lane;                                                \
    { /* prefetch next tile (clamped; junk-safe for idle lanes) */           \
      int qn = sw_ + 1 - lane;                                               \
      qn = qn < 0 ? 0 : (qn > NQ - 1 ? NQ - 1 : qn);                         \
      const float4* bp = &tgt4_s[qn * 4];                                    \
      NXT[0] = bp[0]; NXT[1] = bp[1]; NXT[2] = bp[2]; NXT[3] = bp[3];        \
      NN = tn2_s[qn];                                                        \
    }                                                                        \
    if (q >= 0 && q < NQ) {                                                  \
      v2f seedA; seedA.x = pn0 + CN.x; seedA.y = pn0 + CN.y;                 \
      v2f seedB; seedB.x = pn1 + CN.x; seedB.y = pn1 + CN.y;                 \
      v2f accA = dotpk(seedA, pApk, CUR);                                    \
      v2f accB = dotpk(seedB, pBpk, CUR);                                    \
      float v00 = accA.x + softmin2(carry, a0, l0);                          \
      float v01 = accA.y + softmin2(a0, a1, v00);                            \
      v10 = accB.x + softmin2(l0, v00, l1);                                  \
      v11 = accB.y + softmin2(v00, v01, v10);                                \
      l0 = v01; l1 = v11; carry = a1;                                        \
      if (lane == 63 && w < NW - 1)                                          \
        buf_s[w * NQ + q] = make_float2(v10, v11);                           \
      if (t == NTH - 1 && q == NQ - 1) ws[b] = v11 * LN2F;                   \
    }                                                                        \
    if (lane == 63 && w < NW - 1 && ((sw_ & 3) == 3 || sw_ == WSTEPS - 1))   \
      __hip_atomic_store(&prog_s[w], sw_, __ATOMIC_RELEASE,                  \
                         __HIP_MEMORY_SCOPE_WORKGROUP);                      \
  }

__global__ __launch_bounds__(NTH) void sdtw_kernel(const float* __restrict__ pred,
                                                   const float* __restrict__ target,
                                                   float* __restrict__ ws) {
  __shared__ float4 tgt4_s[NQ * 4];       // 32 KiB, dim-interleaved tiles
  __shared__ float2 tn2_s[NQ];            // 4 KiB scaled norms
  __shared__ float2 buf_s[(NW - 1) * NQ]; // 28 KiB handoff
  __shared__ int prog_s[NW];

  const int t    = threadIdx.x;
  const int w    = t >> 6;
  const int lane = t & 63;
  const int b    = blockIdx.x;
  const float* pr = pred + (size_t)b * T * 8;
  const float* tg = target + (size_t)b * T * 8;

  // ---- stage target tiles: thread t owns tile t (target rows 2t, 2t+1) ----
  // chunk k = {A[2k], B[2k], A[2k+1], B[2k+1]} * (-2*log2e); A=row 2t, B=2t+1
  {
    const float4* tg4 = reinterpret_cast<const float4*>(tg);
    float4 v0 = tg4[t * 4 + 0]; // A d0-3
    float4 v1 = tg4[t * 4 + 1]; // A d4-7
    float4 v2 = tg4[t * 4 + 2]; // B d0-3
    float4 v3 = tg4[t * 4 + 3]; // B d4-7
    float tn0 = (v0.x * v0.x + v0.y * v0.y) + (v0.z * v0.z + v0.w * v0.w) +
                (v1.x * v1.x + v1.y * v1.y) + (v1.z * v1.z + v1.w * v1.w);
    float tn1 = (v2.x * v2.x + v2.y * v2.y) + (v2.z * v2.z + v2.w * v2.w) +
                (v3.x * v3.x + v3.y * v3.y) + (v3.z * v3.z + v3.w * v3.w);
    const float s = -2.0f * L2EF;
    tgt4_s[t * 4 + 0] = make_float4(v0.x * s, v2.x * s, v0.y * s, v2.y * s);
    tgt4_s[t * 4 + 1] = make_float4(v0.z * s, v2.z * s, v0.w * s, v2.w * s);
    tgt4_s[t * 4 + 2] = make_float4(v1.x * s, v3.x * s, v1.y * s, v3.y * s);
    tgt4_s[t * 4 + 3] = make_float4(v1.z * s, v3.z * s, v1.w * s, v3.w * s);
    tn2_s[t] = make_float2(tn0 * L2EF, tn1 * L2EF);
  }
  if (t < NW) prog_s[t] = -1;

  // ---- pred rows -> duplicated pair registers + scaled norms ---------------
  const float4* pr4 = reinterpret_cast<const float4*>(pr);
  float4 pA0 = pr4[t * 4 + 0];
  float4 pA1 = pr4[t * 4 + 1];
  float4 pB0 = pr4[t * 4 + 2];
  float4 pB1 = pr4[t * 4 + 3];
  float pn0 = ((pA0.x * pA0.x + pA0.y * pA0.y) + (pA0.z * pA0.z + pA0.w * pA0.w) +
               (pA1.x * pA1.x + pA1.y * pA1.y) + (pA1.z * pA1.z + pA1.w * pA1.w)) * L2EF;
  float pn1 = ((pB0.x * pB0.x + pB0.y * pB0.y) + (pB0.z * pB0.z + pB0.w * pB0.w) +
               (pB1.x * pB1.x + pB1.y * pB1.y) + (pB1.z * pB1.z + pB1.w * pB1.w)) * L2EF;
  v2f pApk[8], pBpk[8];
  pApk[0].x = pA0.x; pApk[0].y = pA0.x;  pApk[1].x = pA0.y; pApk[1].y = pA0.y;
  pApk[2].x = pA0.z; pApk[2].y = pA0.z;  pApk[3].x = pA0.w; pApk[3].y = pA0.w;
  pApk[4].x = pA1.x; pApk[4].y = pA1.x;  pApk[5].x = pA1.y; pApk[5].y = pA1.y;
  pApk[6].x = pA1.z; pApk[6].y = pA1.z;  pApk[7].x = pA1.w; pApk[7].y = pA1.w;
  pBpk[0].x = pB0.x; pBpk[0].y = pB0.x;  pBpk[1].x = pB0.y; pBpk[1].y = pB0.y;
  pBpk[2].x = pB0.z; pBpk[2].y = pB0.z;  pBpk[3].x = pB0.w; pBpk[3].y = pB0.w;
  pBpk[4].x = pB1.x; pBpk[4].y = pB1.x;  pBpk[5].x = pB1.y; pBpk[5].y = pB1.y;
  pBpk[6].x = pB1.z; pBpk[6].y = pB1.z;  pBpk[7].x = pB1.w; pBpk[7].y = pB1.w;

  __syncthreads(); // staging complete (only block-wide barrier)

  // ---- DP state ------------------------------------------------------------
  float l0 = BIGF, l1 = BIGF;            // left edge R[2t][j-1], R[2t+1][j-1]
  float carry = (t == 0) ? 0.0f : BIGF;  // diag R[2t-1][j-1]; R[-1][-1]=0
  float v10 = BIGF, v11 = BIGF;          // bottom-row outputs (shuffled down)
  int seen = -1;

  float4 tgA[4], tgB[4];
  float2 tnA, tnB;
  { // preload tile 0 for sw=0 (all lanes clamp to q=0)
    tgA[0] = tgt4_s[0]; tgA[1] = tgt4_s[1]; tgA[2] = tgt4_s[2]; tgA[3] = tgt4_s[3];
    tnA = tn2_s[0];
  }

  for (int sw = 0; sw < 576; sw += 2) { // 576 >= WSTEPS; extra step is inert
    STEP(sw, tgA, tnA, tgB, tnB)
    STEP(sw + 1, tgB, tnB, tgA, tnA)
  }
}

__global__ void sdtw_reduce(const float* __restrict__ ws, float* __restrict__ out) {
  int l = threadIdx.x; // 64 threads = one wave
  float v = ws[l];
#pragma unroll
  for (int k = 32; k >= 1; k >>= 1) v += __shfl_down(v, k, 64);
  if (l == 0) out[0] = v * (1.0f / (float)NB);
}

extern "C" void kernel_launch(void* const* d_in, const int* in_sizes, int n_in,
                              void* d_out, int out_size, void* d_ws, size_t ws_size,
                              hipStream_t stream) {
  const float* pred   = (const float*)d_in[0];
  const float* target = (const float*)d_in[1];
  float* out = (float*)d_out;
  float* ws  = (float*)d_ws;

  sdtw_kernel<<<NB, NTH, 0, stream>>>(pred, target, ws);
  sdtw_reduce<<<1, 64, 0, stream>>>(ws, out);
}

// Round 6
// 403.975 us; speedup vs baseline: 2.4903x; 1.1109x over previous
//
#include <hip/hip_runtime.h>

// SoftDTW forward, B=64, T=1024, D=8, gamma=1.0, out = mean over batch of R[T,T].
//
// R6: LDS-pressure restructure. R5 post-mortem showed the LDS data pipe
// (8 waves x ~6 ds_reads x 12cyc = ~576 cyc/period) + conflicts, not VALU
// issue, bound the period. Changes:
//  - 256 threads / 4 waves per block; thread t owns FOUR rows 4t..4t+3.
//    Same 80B tile read now feeds 8 cells (was 4); only 4 waves share the
//    LDS pipe -> ~4x less LDS pressure per cell. Stagger 7->3 boundaries.
//  - tile restored to 5 x float4 (80B stride = 20-bank, R4-proven 0.6M
//    conflicts; R5's 64B stride was a 12.7M-conflict regression).
//  - cell math (3-trans softmin, pk_fma dots) and cross-wave sync protocol
//    byte-identical to R5.

typedef float v2f __attribute__((ext_vector_type(2)));

static constexpr int T      = 1024;
static constexpr int NB     = 64;
static constexpr int NTH    = 256;       // 4 waves
static constexpr int NW     = 4;
static constexpr int CT     = 2;
static constexpr int NQ     = T / CT;    // 512 col-tiles
static constexpr int WSTEPS = NQ + 63;   // 575 per-wave staircase steps

#define BIGF 1e10f
#define L2EF 1.4426950408889634f
#define LN2F 0.6931471805599453f

__device__ __forceinline__ float fexp2(float x) { return __builtin_amdgcn_exp2f(x); }
__device__ __forceinline__ float flog2(float x) { return __builtin_amdgcn_logf(x); }

// softmin in base-2 domain, 3 trans: m - log2(1 + 2^(m-med) + 2^(m-max)).
__device__ __forceinline__ float softmin2(float a, float b, float c) {
  float m = fminf(fminf(a, b), c);
  float M = fmaxf(fmaxf(a, b), c);
  float e = __builtin_amdgcn_fmed3f(a, b, c);
  float s = fexp2(m - e) + fexp2(m - M);
  return m - flog2(1.0f + s);
}

__device__ __forceinline__ v2f pkfma(v2f a, v2f b, v2f c) {
  v2f d;
  asm("v_pk_fma_f32 %0, %1, %2, %3" : "=v"(d) : "v"(a), "v"(b), "v"(c));
  return d;
}

__device__ __forceinline__ v2f lo2(const float4& c) { v2f r; r.x = c.x; r.y = c.y; return r; }
__device__ __forceinline__ v2f hi2(const float4& c) { v2f r; r.x = c.z; r.y = c.w; return r; }

// (dot_col0, dot_col1) for one pred row (dup pairs pp[0..7]) vs interleaved
// tile chunks C[0..3]; seed = (pn+tn0, pn+tn1), everything pre-scaled.
__device__ __forceinline__ v2f dotpk(v2f seed, const v2f* pp, const float4* C) {
  v2f a = seed;
  a = pkfma(pp[0], lo2(C[0]), a);
  a = pkfma(pp[1], hi2(C[0]), a);
  a = pkfma(pp[2], lo2(C[1]), a);
  a = pkfma(pp[3], hi2(C[1]), a);
  a = pkfma(pp[4], lo2(C[2]), a);
  a = pkfma(pp[5], hi2(C[2]), a);
  a = pkfma(pp[6], lo2(C[3]), a);
  a = pkfma(pp[7], hi2(C[3]), a);
  return a;
}

// One staircase step: 4 rows x 2 cols of cells. CUR/NXT: float4[5] reg tiles
// (chunk 4 = scaled norms in .x/.y).
#define STEP(SW, CUR, NXT)                                                   \
  {                                                                          \
    const int sw_ = (SW);                                                    \
    float2 cb = make_float2(BIGF, BIGF);                                     \
    if (w > 0 && sw_ < NQ) {                                                 \
      if ((sw_ & 3) == 0) {                                                  \
        const int need = ((sw_ + 3 < NQ) ? sw_ + 3 : NQ - 1) + 63;           \
        while (seen < need) {                                                 \
          seen = __hip_atomic_load(&prog_s[w - 1], __ATOMIC_ACQUIRE,         \
                                   __HIP_MEMORY_SCOPE_WORKGROUP);            \
          if (seen < need) __builtin_amdgcn_s_sleep(1);                      \
        }                                                                    \
      }                                                                      \
      cb = buf_s[(w - 1) * NQ + sw_]; /* wave-uniform broadcast read */      \
    }                                                                        \
    float na0 = __shfl_up(vD0, 1, 64);                                       \
    float na1 = __shfl_up(vD1, 1, 64);                                       \
    float a0 = (lane == 0) ? cb.x : na0;                                     \
    float a1 = (lane == 0) ? cb.y : na1;                                     \
    const int q = sw_ - lane;                                                \
    { /* prefetch next tile (clamped; junk-safe for idle lanes) */           \
      int qn = sw_ + 1 - lane;                                               \
      qn = qn < 0 ? 0 : (qn > NQ - 1 ? NQ - 1 : qn);                         \
      const float4* bp = &tgt4_s[qn * 5];                                    \
      NXT[0] = bp[0]; NXT[1] = bp[1]; NXT[2] = bp[2]; NXT[3] = bp[3];        \
      NXT[4] = bp[4];                                                        \
    }                                                                        \
    if (q >= 0 && q < NQ) {                                                  \
      const float tn0 = CUR[4].x, tn1 = CUR[4].y;                            \
      v2f sA; sA.x = pnA + tn0; sA.y = pnA + tn1;                            \
      v2f sB; sB.x = pnB + tn0; sB.y = pnB + tn1;                            \
      v2f sC; sC.x = pnC + tn0; sC.y = pnC + tn1;                            \
      v2f sD; sD.x = pnD + tn0; sD.y = pnD + tn1;                            \
      v2f accA = dotpk(sA, ppA, CUR);                                        \
      v2f accB = dotpk(sB, ppB, CUR);                                        \
      v2f accC = dotpk(sC, ppC, CUR);                                        \
      v2f accD = dotpk(sD, ppD, CUR);                                        \
      float vA0 = accA.x + softmin2(carry, a0, lA);                          \
      float vA1 = accA.y + softmin2(a0, a1, vA0);                            \
      float vB0 = accB.x + softmin2(lA, vA0, lB);                            \
      float vB1 = accB.y + softmin2(vA0, vA1, vB0);                          \
      float vC0 = accC.x + softmin2(lB, vB0, lC);                            \
      float vC1 = accC.y + softmin2(vB0, vB1, vC0);                          \
      vD0 = accD.x + softmin2(lC, vC0, lD);                                  \
      vD1 = accD.y + softmin2(vC0, vC1, vD0);                                \
      lA = vA1; lB = vB1; lC = vC1; lD = vD1; carry = a1;                    \
      if (lane == 63 && w < NW - 1)                                          \
        buf_s[w * NQ + q] = make_float2(vD0, vD1);                           \
      if (t == NTH - 1 && q == NQ - 1) ws[b] = vD1 * LN2F;                   \
    }                                                                        \
    if (lane == 63 && w < NW - 1 && ((sw_ & 3) == 3 || sw_ == WSTEPS - 1))   \
      __hip_atomic_store(&prog_s[w], sw_, __ATOMIC_RELEASE,                  \
                         __HIP_MEMORY_SCOPE_WORKGROUP);                      \
  }

__global__ __launch_bounds__(NTH) void sdtw_kernel(const float* __restrict__ pred,
                                                   const float* __restrict__ target,
                                                   float* __restrict__ ws) {
  __shared__ float4 tgt4_s[NQ * 5];       // 40 KiB, 80B-stride tiles
  __shared__ float2 buf_s[(NW - 1) * NQ]; // 12 KiB handoff
  __shared__ int prog_s[NW];

  const int t    = threadIdx.x;
  const int w    = t >> 6;
  const int lane = t & 63;
  const int b    = blockIdx.x;
  const float* pr = pred + (size_t)b * T * 8;
  const float* tg = target + (size_t)b * T * 8;

  // ---- stage target: thread t stages tiles 2t, 2t+1 (rows 4t..4t+3) ------
  // tile chunk k = {A[2k], B[2k], A[2k+1], B[2k+1]} * (-2*log2e); chunk 4 =
  // (|A|^2*log2e, |B|^2*log2e, 0, 0). A = row 2q, B = row 2q+1.
  {
    const float4* tg4 = reinterpret_cast<const float4*>(tg);
    const float s = -2.0f * L2EF;
#pragma unroll
    for (int h = 0; h < 2; ++h) { // tile 2t+h
      float4 u0 = tg4[t * 8 + 4 * h + 0]; // A d0-3
      float4 u1 = tg4[t * 8 + 4 * h + 1]; // A d4-7
      float4 u2 = tg4[t * 8 + 4 * h + 2]; // B d0-3
      float4 u3 = tg4[t * 8 + 4 * h + 3]; // B d4-7
      float tA = (u0.x * u0.x + u0.y * u0.y) + (u0.z * u0.z + u0.w * u0.w) +
                 (u1.x * u1.x + u1.y * u1.y) + (u1.z * u1.z + u1.w * u1.w);
      float tB = (u2.x * u2.x + u2.y * u2.y) + (u2.z * u2.z + u2.w * u2.w) +
                 (u3.x * u3.x + u3.y * u3.y) + (u3.z * u3.z + u3.w * u3.w);
      float4* dst = &tgt4_s[(2 * t + h) * 5];
      dst[0] = make_float4(u0.x * s, u2.x * s, u0.y * s, u2.y * s);
      dst[1] = make_float4(u0.z * s, u2.z * s, u0.w * s, u2.w * s);
      dst[2] = make_float4(u1.x * s, u3.x * s, u1.y * s, u3.y * s);
      dst[3] = make_float4(u1.z * s, u3.z * s, u1.w * s, u3.w * s);
      dst[4] = make_float4(tA * L2EF, tB * L2EF, 0.0f, 0.0f);
    }
  }
  if (t < NW) prog_s[t] = -1;

  // ---- pred rows 4t..4t+3 -> duplicated pair registers + scaled norms -----
  const float4* pr4 = reinterpret_cast<const float4*>(pr);
  float4 qA0 = pr4[t * 8 + 0], qA1 = pr4[t * 8 + 1];
  float4 qB0 = pr4[t * 8 + 2], qB1 = pr4[t * 8 + 3];
  float4 qC0 = pr4[t * 8 + 4], qC1 = pr4[t * 8 + 5];
  float4 qD0 = pr4[t * 8 + 6], qD1 = pr4[t * 8 + 7];
#define NRM(a, b)                                                            \
  (((a.x * a.x + a.y * a.y) + (a.z * a.z + a.w * a.w) +                      \
    (b.x * b.x + b.y * b.y) + (b.z * b.z + b.w * b.w)) * L2EF)
  float pnA = NRM(qA0, qA1), pnB = NRM(qB0, qB1);
  float pnC = NRM(qC0, qC1), pnD = NRM(qD0, qD1);
#define DUP(pp, r0, r1)                                                      \
  pp[0].x = r0.x; pp[0].y = r0.x; pp[1].x = r0.y; pp[1].y = r0.y;            \
  pp[2].x = r0.z; pp[2].y = r0.z; pp[3].x = r0.w; pp[3].y = r0.w;            \
  pp[4].x = r1.x; pp[4].y = r1.x; pp[5].x = r1.y; pp[5].y = r1.y;            \
  pp[6].x = r1.z; pp[6].y = r1.z; pp[7].x = r1.w; pp[7].y = r1.w;
  v2f ppA[8], ppB[8], ppC[8], ppD[8];
  DUP(ppA, qA0, qA1) DUP(ppB, qB0, qB1) DUP(ppC, qC0, qC1) DUP(ppD, qD0, qD1)

  __syncthreads(); // staging complete (only block-wide barrier)

  // ---- DP state ------------------------------------------------------------
  float lA = BIGF, lB = BIGF, lC = BIGF, lD = BIGF; // left edges rows 4t..4t+3
  float carry = (t == 0) ? 0.0f : BIGF;             // diag R[4t-1][j-1]
  float vD0 = BIGF, vD1 = BIGF;                     // bottom row (shuffled down)
  int seen = -1;

  float4 tgA[5], tgB[5];
  { // preload tile 0 for sw=0 (all lanes clamp to q=0)
    tgA[0] = tgt4_s[0]; tgA[1] = tgt4_s[1]; tgA[2] = tgt4_s[2];
    tgA[3] = tgt4_s[3]; tgA[4] = tgt4_s[4];
  }

  for (int sw = 0; sw < 576; sw += 2) { // 576 >= WSTEPS; extra step is inert
    STEP(sw, tgA, tgB)
    STEP(sw + 1, tgB, tgA)
  }
}

__global__ void sdtw_reduce(const float* __restrict__ ws, float* __restrict__ out) {
  int l = threadIdx.x; // 64 threads = one wave
  float v = ws[l];
#pragma unroll
  for (int k = 32; k >= 1; k >>= 1) v += __shfl_down(v, k, 64);
  if (l == 0) out[0] = v * (1.0f / (float)NB);
}

extern "C" void kernel_launch(void* const* d_in, const int* in_sizes, int n_in,
                              void* d_out, int out_size, void* d_ws, size_t ws_size,
                              hipStream_t stream) {
  const float* pred   = (const float*)d_in[0];
  const float* target = (const float*)d_in[1];
  float* out = (float*)d_out;
  float* ws  = (float*)d_ws;

  sdtw_kernel<<<NB, NTH, 0, stream>>>(pred, target, ws);
  sdtw_reduce<<<1, 64, 0, stream>>>(ws, out);
}